// Round 1
// baseline (250.151 us; speedup 1.0000x reference)
//
#include <hip/hip_runtime.h>

#define GRID3 32768  // 32^3
#define FDIM 64

// Order-preserving float<->uint encoding (monotonic: enc(a)<enc(b) iff a<b)
__device__ __forceinline__ unsigned int enc_f32(float f) {
    unsigned int u = __float_as_uint(f);
    return (u & 0x80000000u) ? ~u : (u | 0x80000000u);
}
__device__ __forceinline__ float dec_f32(unsigned int u) {
    u = (u & 0x80000000u) ? (u ^ 0x80000000u) : ~u;
    return __uint_as_float(u);
}

__global__ void init_ws_kernel(unsigned int* ws) {
    ws[0] = 0xFFFFFFFFu;  // encoded min accumulator (starts at +inf-equivalent)
    ws[1] = 0u;           // encoded max accumulator (starts at -inf-equivalent)
}

__global__ void minmax_kernel(const float* __restrict__ pts, int n,
                              unsigned int* __restrict__ ws) {
    float lmin = INFINITY, lmax = -INFINITY;
    for (int i = blockIdx.x * blockDim.x + threadIdx.x; i < n;
         i += gridDim.x * blockDim.x) {
        float v = pts[i];
        lmin = fminf(lmin, v);
        lmax = fmaxf(lmax, v);
    }
    __shared__ float smin[256], smax[256];
    smin[threadIdx.x] = lmin;
    smax[threadIdx.x] = lmax;
    __syncthreads();
    for (int s = 128; s > 0; s >>= 1) {
        if (threadIdx.x < (unsigned)s) {
            smin[threadIdx.x] = fminf(smin[threadIdx.x], smin[threadIdx.x + s]);
            smax[threadIdx.x] = fmaxf(smax[threadIdx.x], smax[threadIdx.x + s]);
        }
        __syncthreads();
    }
    if (threadIdx.x == 0) {
        atomicMin(&ws[0], enc_f32(smin[0]));
        atomicMax(&ws[1], enc_f32(smax[0]));
    }
}

// One 64-lane wave per point; lane = feature channel. 4 points per 256-block.
__global__ void scatter_kernel(const float* __restrict__ pts,
                               const float* __restrict__ feat,
                               const unsigned int* __restrict__ ws,
                               unsigned int* __restrict__ out,
                               int ntot, int N) {
    int lane = threadIdx.x & 63;
    int p = blockIdx.x * 4 + (threadIdx.x >> 6);
    if (p >= ntot) return;

    float pmin = dec_f32(ws[0]);
    float pmax = dec_f32(ws[1]);
    float denom = pmax - pmin + 1e-6f;

    // All 64 lanes read the same 3 floats -> broadcast from L1, cheap.
    float x = pts[p * 3 + 0];
    float y = pts[p * 3 + 1];
    float z = pts[p * 3 + 2];

    // Match reference op order exactly: normed = (v - pmin)/denom; floor(normed*32)
    int vx = (int)floorf(((x - pmin) / denom) * 32.0f);
    int vy = (int)floorf(((y - pmin) / denom) * 32.0f);
    int vz = (int)floorf(((z - pmin) / denom) * 32.0f);
    vx = min(max(vx, 0), 31);
    vy = min(max(vy, 0), 31);
    vz = min(max(vz, 0), 31);
    int gidx = vx * 1024 + vy * 32 + vz;

    int b = p / N;
    float f = feat[(size_t)p * FDIM + lane];  // coalesced: lane == channel

    // Grid starts at 0 and reference maxes against 0 => negative f never wins.
    // Positive IEEE floats order identically to their uint bit patterns.
    if (f > 0.0f) {
        unsigned int* addr = out + ((size_t)b * GRID3 + gidx) * FDIM + lane;
        atomicMax(addr, __float_as_uint(f));
    }
}

extern "C" void kernel_launch(void* const* d_in, const int* in_sizes, int n_in,
                              void* d_out, int out_size, void* d_ws, size_t ws_size,
                              hipStream_t stream) {
    const float* pts = (const float*)d_in[0];
    const float* feat = (const float*)d_in[1];
    unsigned int* ws = (unsigned int*)d_ws;

    int npts3 = in_sizes[0];      // B*N*3
    int ntot = npts3 / 3;         // B*N
    int B = out_size / (GRID3 * FDIM);
    int N = ntot / B;

    hipLaunchKernelGGL(init_ws_kernel, dim3(1), dim3(1), 0, stream, ws);
    hipLaunchKernelGGL(minmax_kernel, dim3(512), dim3(256), 0, stream,
                       pts, npts3, ws);
    hipMemsetAsync(d_out, 0, (size_t)out_size * sizeof(float), stream);
    int blocks = (ntot + 3) / 4;
    hipLaunchKernelGGL(scatter_kernel, dim3(blocks), dim3(256), 0, stream,
                       pts, feat, ws, (unsigned int*)d_out, ntot, N);
}